// Round 1
// baseline (356.560 us; speedup 1.0000x reference)
//
#include <hip/hip_runtime.h>

typedef __attribute__((ext_vector_type(8))) short short8;
typedef __attribute__((ext_vector_type(4))) float f32x4;

#define GLOAD16(g, l)                                                          \
  __builtin_amdgcn_global_load_lds(                                            \
      (const __attribute__((address_space(1))) unsigned int*)(g),              \
      (__attribute__((address_space(3))) unsigned int*)(l), 16, 0, 0)

__device__ __forceinline__ unsigned short f2bf(float f) {
  unsigned int u = __float_as_uint(f);
  u += 0x7FFFu + ((u >> 16) & 1u);   // RNE
  return (unsigned short)(u >> 16);
}

// ---------------------------------------------------------------- mix / bmix
// mix[s,q] = softmax_s(amp)[s,q] * cos(phase[s,q]);  bmix = bias * mix
__global__ void mix_kernel(const float* __restrict__ amp,
                           const float* __restrict__ phase,
                           const float* __restrict__ bias,
                           float* __restrict__ mix, float* __restrict__ bmix) {
  int q = blockIdx.x * blockDim.x + threadIdx.x;  // 0..1023
  float a[16];
  float mx = -1e30f;
  for (int s = 0; s < 16; ++s) {
    a[s] = amp[s * 1024 + q];
    mx = fmaxf(mx, a[s]);
  }
  float sum = 0.f;
  for (int s = 0; s < 16; ++s) {
    a[s] = __expf(a[s] - mx);
    sum += a[s];
  }
  float inv = 1.f / sum;
  for (int s = 0; s < 16; ++s) {
    float m = a[s] * inv * cosf(phase[s * 1024 + q]);
    mix[s * 1024 + q] = m;
    bmix[s * 1024 + q] = bias[s * 1024 + q] * m;
  }
}

// ---------------------------------------------------------------- cast x->bf16
__global__ void cast_x_kernel(const float* __restrict__ x,
                              unsigned short* __restrict__ xb) {
  int i = (blockIdx.x * blockDim.x + threadIdx.x) * 4;
  float4 v = *(const float4*)(x + i);
  union { unsigned short h[4]; uint2 u; } o;
  o.h[0] = f2bf(v.x); o.h[1] = f2bf(v.y); o.h[2] = f2bf(v.z); o.h[3] = f2bf(v.w);
  *(uint2*)(xb + i) = o.u;
}

// ------------------------------------------------- transpose+cast W -> Wt bf16
// W[s][i][q] f32  ->  Wt[s][q][i] bf16   (so the GEMM B^T operand is K-contig)
__global__ void transpose_w_kernel(const float* __restrict__ W,
                                   unsigned short* __restrict__ Wt) {
  __shared__ unsigned short tile[32][33];
  int s = blockIdx.z;
  int q0 = blockIdx.x * 32, i0 = blockIdx.y * 32;
  const float* Ws = W + (size_t)s * 1024 * 1024;
  unsigned short* Wts = Wt + (size_t)s * 1024 * 1024;
  int tx = threadIdx.x, ty = threadIdx.y;
  #pragma unroll
  for (int j = 0; j < 32; j += 8)
    tile[ty + j][tx] = f2bf(Ws[(size_t)(i0 + ty + j) * 1024 + q0 + tx]);
  __syncthreads();
  #pragma unroll
  for (int j = 0; j < 32; j += 8)
    Wts[(size_t)(q0 + ty + j) * 1024 + i0 + tx] = tile[tx][ty + j];
}

// ---------------------------------------------------------------- bf16 GEMM
// C[b][n] = sum_k xb[b][k] * Wt[n][k],  n = s*1024+q,  epilogue: *mix + bmix
// 128x128 tile, BK=32, 4 waves (2x2), 16x16x32 MFMA, global_load_lds staging.
__global__ __launch_bounds__(256) void gemm_kernel(
    const unsigned short* __restrict__ xb, const unsigned short* __restrict__ wt,
    const float* __restrict__ mix, const float* __restrict__ bmix,
    float* __restrict__ out) {
  __shared__ __align__(16) unsigned short Abuf[2][128 * 32];
  __shared__ __align__(16) unsigned short Bbuf[2][128 * 32];

  const int tid = threadIdx.x;
  const int lane = tid & 63;
  const int wv = tid >> 6;
  const int wm = wv >> 1, wn = wv & 1;
  const int m0 = blockIdx.y * 128;
  const int n0 = blockIdx.x * 128;

  // staging geometry: chunk c covers tile row c/4, 8 bf16 at col (c%4)*8
  const int c0 = tid, c1 = tid + 256;
  const int r0 = c0 >> 2, k80 = (c0 & 3) * 8;
  const int r1 = c1 >> 2, k81 = (c1 & 3) * 8;
  const unsigned short* ga0 = xb + (size_t)(m0 + r0) * 1024 + k80;
  const unsigned short* ga1 = xb + (size_t)(m0 + r1) * 1024 + k81;
  const unsigned short* gb0 = wt + (size_t)(n0 + r0) * 1024 + k80;
  const unsigned short* gb1 = wt + (size_t)(n0 + r1) * 1024 + k81;

  f32x4 acc[4][4];
  #pragma unroll
  for (int i = 0; i < 4; ++i)
    #pragma unroll
    for (int j = 0; j < 4; ++j) acc[i][j] = (f32x4){0.f, 0.f, 0.f, 0.f};

  // prologue: stage k-tile 0 into buffer 0
  GLOAD16(ga0, &Abuf[0][c0 * 8]);
  GLOAD16(ga1, &Abuf[0][c1 * 8]);
  GLOAD16(gb0, &Bbuf[0][c0 * 8]);
  GLOAD16(gb1, &Bbuf[0][c1 * 8]);
  asm volatile("s_waitcnt vmcnt(0)" ::: "memory");
  __syncthreads();

  const int lr = lane & 15;
  const int lk = (lane >> 4) * 8;
  int cur = 0;
  for (int kt = 0; kt < 32; ++kt) {
    if (kt < 31) {
      const int ko = (kt + 1) * 32;
      GLOAD16(ga0 + ko, &Abuf[cur ^ 1][c0 * 8]);
      GLOAD16(ga1 + ko, &Abuf[cur ^ 1][c1 * 8]);
      GLOAD16(gb0 + ko, &Bbuf[cur ^ 1][c0 * 8]);
      GLOAD16(gb1 + ko, &Bbuf[cur ^ 1][c1 * 8]);
    }
    short8 af[4], bfr[4];
    #pragma unroll
    for (int mi = 0; mi < 4; ++mi)
      af[mi] = *(const short8*)&Abuf[cur][(wm * 64 + mi * 16 + lr) * 32 + lk];
    #pragma unroll
    for (int ni = 0; ni < 4; ++ni)
      bfr[ni] = *(const short8*)&Bbuf[cur][(wn * 64 + ni * 16 + lr) * 32 + lk];
    #pragma unroll
    for (int mi = 0; mi < 4; ++mi)
      #pragma unroll
      for (int ni = 0; ni < 4; ++ni)
        acc[mi][ni] = __builtin_amdgcn_mfma_f32_16x16x32_bf16(
            af[mi], bfr[ni], acc[mi][ni], 0, 0, 0);
    asm volatile("s_waitcnt vmcnt(0)" ::: "memory");
    __syncthreads();
    cur ^= 1;
  }

  // epilogue: sup = acc*mix + bmix, f32 to out (LN kernel normalizes in place)
  #pragma unroll
  for (int ni = 0; ni < 4; ++ni) {
    const int n = n0 + wn * 64 + ni * 16 + lr;
    const float mv = mix[n];
    const float bv = bmix[n];
    #pragma unroll
    for (int mi = 0; mi < 4; ++mi) {
      const int m = m0 + wm * 64 + mi * 16 + (lane >> 4) * 4;
      #pragma unroll
      for (int r = 0; r < 4; ++r)
        out[(size_t)(m + r) * 16384 + n] = acc[mi][ni][r] * mv + bv;
    }
  }
}

// ---------------------------------------------------------------- in-place LN
// one block per (b,s) row of 1024 f32
__global__ __launch_bounds__(256) void ln_kernel(float* __restrict__ out,
                                                 const float* __restrict__ gamma,
                                                 const float* __restrict__ beta) {
  __shared__ float red[8];
  const int t = threadIdx.x;
  const size_t base = (size_t)blockIdx.x * 1024;
  float4 v = *(const float4*)(out + base + t * 4);
  float s = v.x + v.y + v.z + v.w;
  float ss = v.x * v.x + v.y * v.y + v.z * v.z + v.w * v.w;
  #pragma unroll
  for (int m = 32; m >= 1; m >>= 1) {
    s += __shfl_xor(s, m);
    ss += __shfl_xor(ss, m);
  }
  const int wv = t >> 6;
  if ((t & 63) == 0) { red[wv * 2] = s; red[wv * 2 + 1] = ss; }
  __syncthreads();
  const float S = red[0] + red[2] + red[4] + red[6];
  const float SS = red[1] + red[3] + red[5] + red[7];
  const float mean = S * (1.0f / 1024.0f);
  const float var = SS * (1.0f / 1024.0f) - mean * mean;
  const float rstd = rsqrtf(var + 1e-5f);
  const float4 g = *(const float4*)(gamma + t * 4);
  const float4 b = *(const float4*)(beta + t * 4);
  float4 o;
  o.x = (v.x - mean) * rstd * g.x + b.x;
  o.y = (v.y - mean) * rstd * g.y + b.y;
  o.z = (v.z - mean) * rstd * g.z + b.z;
  o.w = (v.w - mean) * rstd * g.w + b.w;
  *(float4*)(out + base + t * 4) = o;
}

extern "C" void kernel_launch(void* const* d_in, const int* in_sizes, int n_in,
                              void* d_out, int out_size, void* d_ws, size_t ws_size,
                              hipStream_t stream) {
  (void)in_sizes; (void)n_in; (void)out_size; (void)ws_size;
  const float* x     = (const float*)d_in[0];  // [4096,1024]
  const float* W     = (const float*)d_in[1];  // [16,1024,1024]
  const float* bias  = (const float*)d_in[2];  // [16,1024]
  const float* amp   = (const float*)d_in[3];  // [16,1024]
  const float* phase = (const float*)d_in[4];  // [16,1024]
  const float* gamma = (const float*)d_in[5];  // [1024]
  const float* beta  = (const float*)d_in[6];  // [1024]
  float* out = (float*)d_out;                  // [4096,16,1024]

  char* ws = (char*)d_ws;
  unsigned short* Wt = (unsigned short*)ws;                       // 33,554,432 B
  unsigned short* xb = (unsigned short*)(ws + 33554432);          //  8,388,608 B
  float* mix  = (float*)(ws + 33554432 + 8388608);                //     65,536 B
  float* bmix = mix + 16384;                                      //     65,536 B

  hipLaunchKernelGGL(mix_kernel, dim3(4), dim3(256), 0, stream, amp, phase, bias, mix, bmix);
  hipLaunchKernelGGL(cast_x_kernel, dim3(4096), dim3(256), 0, stream, x, xb);
  hipLaunchKernelGGL(transpose_w_kernel, dim3(32, 32, 16), dim3(32, 8), 0, stream, W, Wt);
  hipLaunchKernelGGL(gemm_kernel, dim3(128, 32), dim3(256), 0, stream, xb, Wt, mix, bmix, out);
  hipLaunchKernelGGL(ln_kernel, dim3(65536), dim3(256), 0, stream, out, gamma, beta);
}